// Round 1
// baseline (704.822 us; speedup 1.0000x reference)
//
#include <hip/hip_runtime.h>

// ---------- helpers ----------
typedef __bf16 bf16x8 __attribute__((ext_vector_type(8)));
typedef float f32x4 __attribute__((ext_vector_type(4)));

__device__ __forceinline__ float bf2f(unsigned short u) {
  union { unsigned int i; float f; } x;
  x.i = ((unsigned int)u) << 16;
  return x.f;
}
__device__ __forceinline__ unsigned short f2bf(float f) {
  union { float f; unsigned int i; } x;
  x.f = f;
  unsigned int u = x.i;
  u += 0x7fffu + ((u >> 16) & 1u);  // RNE
  return (unsigned short)(u >> 16);
}

// async global->LDS, 16B per lane, LDS dest must be wave-uniform base (lane auto-offsets by 16B)
__device__ __forceinline__ void load16_to_lds(const void* g, void* l) {
  __builtin_amdgcn_global_load_lds(
      (__attribute__((address_space(1))) void*)const_cast<void*>(g),
      (__attribute__((address_space(3))) void*)l, 16, 0, 0);
}

// ---------- cast fp32 -> bf16 (vectorized x4) ----------
__global__ __launch_bounds__(256) void cast_f32_to_bf16(const float* __restrict__ src,
                                                        unsigned short* __restrict__ dst,
                                                        int n4) {
  int i = blockIdx.x * 256 + threadIdx.x;
  if (i < n4) {
    float4 f = ((const float4*)src)[i];
    ushort4 o;
    o.x = f2bf(f.x); o.y = f2bf(f.y); o.z = f2bf(f.z); o.w = f2bf(f.w);
    ((ushort4*)dst)[i] = o;
  }
}

// ---------- NT GEMM: C[m][n] = sum_k A[m][k] * B[n][k] ----------
// m97 structure: 128x128 tile, BK=32, 4 waves each own 64x64 (4x4 MFMA 16x16x32 subtiles).
// MODE 0: proj     -> bf16 out, full K
// MODE 1: scores   -> bf16 out * scale, skip blocks above diagonal
// MODE 2: PV       -> f32 out, K-loop clipped at causal diagonal (kEnd = 128*(by+1))
template <int MODE>
__global__ __launch_bounds__(256) void gemm_nt(const unsigned short* __restrict__ A, int lda,
                                               const unsigned short* __restrict__ B, int ldb,
                                               void* __restrict__ Cv, int ldc, int K, float scale,
                                               long long sA, long long sB, long long sC) {
  if (MODE == 1 && blockIdx.x > blockIdx.y) return;  // strictly-upper causal blocks: skip
  A += (long long)blockIdx.z * sA;
  B += (long long)blockIdx.z * sB;
  const int rowBase = blockIdx.y * 128;
  const int colBase = blockIdx.x * 128;
  __shared__ unsigned short As[128 * 32];  // 8 KB, row-major [128][32], no pad (global_load_lds)
  __shared__ unsigned short Bs[128 * 32];

  const int tid = threadIdx.x;
  const int wave = tid >> 6;
  const int lane = tid & 63;

  // staging: per wave 2 issues, each covers 16 tile-rows (1024B contiguous LDS)
  const int slot0 = (wave * 2 + 0) * 512;  // LDS element offset
  const int slot1 = (wave * 2 + 1) * 512;
  const int rS0 = (wave * 2 + 0) * 16 + (lane >> 2);
  const int rS1 = (wave * 2 + 1) * 16 + (lane >> 2);
  const int cS = (lane & 3) * 8;  // 8 bf16 = 16B per lane
  const unsigned short* aG0 = A + (size_t)(rowBase + rS0) * lda + cS;
  const unsigned short* aG1 = A + (size_t)(rowBase + rS1) * lda + cS;
  const unsigned short* bG0 = B + (size_t)(colBase + rS0) * ldb + cS;
  const unsigned short* bG1 = B + (size_t)(colBase + rS1) * ldb + cS;

  // compute: wave (wr,wc) owns 64x64 of C
  const int wr = wave >> 1, wc = wave & 1;
  const int fRow = lane & 15;
  const int fK = (lane >> 4) * 8;

  f32x4 acc[4][4];
#pragma unroll
  for (int i = 0; i < 4; ++i)
#pragma unroll
    for (int j = 0; j < 4; ++j) {
      f32x4 z = {0.f, 0.f, 0.f, 0.f};
      acc[i][j] = z;
    }

  const int kEnd = (MODE == 2) ? (int)(blockIdx.y + 1) * 128 : K;
  for (int k0 = 0; k0 < kEnd; k0 += 32) {
    __syncthreads();  // protect LDS from previous iteration's readers
    load16_to_lds(aG0 + k0, &As[slot0]);
    load16_to_lds(aG1 + k0, &As[slot1]);
    load16_to_lds(bG0 + k0, &Bs[slot0]);
    load16_to_lds(bG1 + k0, &Bs[slot1]);
    __syncthreads();  // compiler emits vmcnt(0) drain before barrier

    bf16x8 af[4], bfr[4];
#pragma unroll
    for (int i = 0; i < 4; ++i)
      af[i] = *(const bf16x8*)&As[(64 * wr + 16 * i + fRow) * 32 + fK];
#pragma unroll
    for (int j = 0; j < 4; ++j)
      bfr[j] = *(const bf16x8*)&Bs[(64 * wc + 16 * j + fRow) * 32 + fK];
#pragma unroll
    for (int i = 0; i < 4; ++i)
#pragma unroll
      for (int j = 0; j < 4; ++j)
        acc[i][j] = __builtin_amdgcn_mfma_f32_16x16x32_bf16(af[i], bfr[j], acc[i][j], 0, 0, 0);
  }

  // epilogue: C/D layout col=lane&15, row=(lane>>4)*4+reg  [m89-verified]
  const int er = (lane >> 4) * 4;
  const int ec = lane & 15;
  if constexpr (MODE == 2) {
    float* C = (float*)Cv + (long long)blockIdx.z * sC;
#pragma unroll
    for (int i = 0; i < 4; ++i)
#pragma unroll
      for (int j = 0; j < 4; ++j) {
        size_t base = (size_t)(rowBase + 64 * wr + 16 * i + er) * ldc +
                      (size_t)(colBase + 64 * wc + 16 * j + ec);
#pragma unroll
        for (int r = 0; r < 4; ++r) C[base + (size_t)r * ldc] = acc[i][j][r];
      }
  } else {
    unsigned short* C = (unsigned short*)Cv + (long long)blockIdx.z * sC;
#pragma unroll
    for (int i = 0; i < 4; ++i)
#pragma unroll
      for (int j = 0; j < 4; ++j) {
        size_t base = (size_t)(rowBase + 64 * wr + 16 * i + er) * ldc +
                      (size_t)(colBase + 64 * wc + 16 * j + ec);
#pragma unroll
        for (int r = 0; r < 4; ++r) C[base + (size_t)r * ldc] = f2bf(acc[i][j][r] * scale);
      }
  }
}

// ---------- in-place causal softmax over bf16 score rows ----------
// Row r: reads j<=r, writes j < 128*(r/128+1) (zeros past the diagonal so PV's
// MFMA over the diagonal 128-block adds exact zeros). Cols beyond that are never read.
__global__ __launch_bounds__(256) void softmax_causal(unsigned short* __restrict__ Sc, int S) {
  const int r = blockIdx.x;
  unsigned short* row = Sc + (size_t)blockIdx.y * S * S + (size_t)r * S;
  const int ncols = ((r >> 7) + 1) << 7;
  const int tid = threadIdx.x;
  const int nIt = (ncols + 255) >> 8;  // <= 16

  float vals[16];
  float m = -1e30f;
  for (int it = 0; it < nIt; ++it) {
    int j = (it << 8) + tid;
    float v = -1e30f;
    if (j <= r) v = bf2f(row[j]);
    vals[it] = v;
    m = fmaxf(m, v);
  }
  __shared__ float red[4];
  for (int off = 32; off; off >>= 1) m = fmaxf(m, __shfl_xor(m, off, 64));
  if ((tid & 63) == 0) red[tid >> 6] = m;
  __syncthreads();
  m = fmaxf(fmaxf(red[0], red[1]), fmaxf(red[2], red[3]));
  __syncthreads();

  float s = 0.f;
  for (int it = 0; it < nIt; ++it) {
    float e = (vals[it] > -1e29f) ? __expf(vals[it] - m) : 0.f;
    vals[it] = e;
    s += e;
  }
  for (int off = 32; off; off >>= 1) s += __shfl_xor(s, off, 64);
  if ((tid & 63) == 0) red[tid >> 6] = s;
  __syncthreads();
  s = red[0] + red[1] + red[2] + red[3];
  float inv = 1.f / s;
  for (int it = 0; it < nIt; ++it) {
    int j = (it << 8) + tid;
    if (j < ncols) row[j] = f2bf(vals[it] * inv);
  }
}

// ---------- launch ----------
extern "C" void kernel_launch(void* const* d_in, const int* in_sizes, int n_in,
                              void* d_out, int out_size, void* d_ws, size_t ws_size,
                              hipStream_t stream) {
  const float* X  = (const float*)d_in[0];
  const float* Wq = (const float*)d_in[1];
  const float* Wk = (const float*)d_in[2];
  const float* Wv = (const float*)d_in[3];
  float* out = (float*)d_out;

  const int Bsz = 4, S = 4096, D = 1024;
  const long long MD = (long long)Bsz * S;  // 16384 total rows

  // ws layout (bf16): Xb[16384x1024] Wb[3x1024x1024] Qb Kb (each 16384x1024) Vt[1024x16384] Sc[nb x 4096x4096]
  unsigned short* Xb = (unsigned short*)d_ws;
  unsigned short* Wb = Xb + MD * D;
  unsigned short* Qb = Wb + 3LL * D * D;
  unsigned short* Kb = Qb + MD * D;
  unsigned short* Vt = Kb + MD * D;
  unsigned short* Sc = Vt + MD * D;

  size_t fixedB = (size_t)(4 * MD * D + 3LL * D * D) * 2;  // ~140.5 MB
  size_t perB = (size_t)S * S * 2;                         // 33.5 MB per batch of scores
  int nb = 1;
  if (ws_size >= fixedB + 4 * perB) nb = 4;
  else if (ws_size >= fixedB + 2 * perB) nb = 2;

  // 1) casts
  cast_f32_to_bf16<<<dim3((unsigned)(MD * D / 4 / 256)), 256, 0, stream>>>(X, Xb, (int)(MD * D / 4));
  cast_f32_to_bf16<<<dim3((unsigned)((long long)D * D / 4 / 256)), 256, 0, stream>>>(Wq, Wb, D * D / 4);
  cast_f32_to_bf16<<<dim3((unsigned)((long long)D * D / 4 / 256)), 256, 0, stream>>>(Wk, Wb + (long long)D * D, D * D / 4);
  cast_f32_to_bf16<<<dim3((unsigned)((long long)D * D / 4 / 256)), 256, 0, stream>>>(Wv, Wb + 2LL * D * D, D * D / 4);

  // 2) Q,K projections: C[s][e] = X[s,:].W[e,:]  (z picks Wq/Wk -> Qb/Kb)
  gemm_nt<0><<<dim3(D / 128, (unsigned)(MD / 128), 2), 256, 0, stream>>>(
      Xb, D, Wb, D, (void*)Qb, D, D, 1.f, 0LL, (long long)D * D, MD * D);
  // 3) V produced transposed: Vt[e][s] = Wv[e,:].X[s,:]
  gemm_nt<0><<<dim3((unsigned)(MD / 128), D / 128, 1), 256, 0, stream>>>(
      Wb + 2LL * D * D, D, Xb, D, (void*)Vt, (int)MD, D, 1.f, 0LL, 0LL, 0LL);

  // 4) per-batch: scores -> softmax -> PV
  const float sscale = 1.0f / 32.0f;  // 1/sqrt(1024)
  for (int b0 = 0; b0 < Bsz; b0 += nb) {
    gemm_nt<1><<<dim3(S / 128, S / 128, nb), 256, 0, stream>>>(
        Qb + (long long)b0 * S * D, D, Kb + (long long)b0 * S * D, D, (void*)Sc, S, D, sscale,
        (long long)S * D, (long long)S * D, (long long)S * S);
    softmax_causal<<<dim3(S, nb), 256, 0, stream>>>(Sc, S);
    gemm_nt<2><<<dim3(D / 128, S / 128, nb), 256, 0, stream>>>(
        Sc, S, Vt + (long long)b0 * S, (int)MD, (void*)(out + (long long)b0 * S * D), D, S, 1.f,
        (long long)S * S, (long long)S, (long long)S * D);
  }
}